// Round 6
// baseline (70.694 us; speedup 1.0000x reference)
//
#include <hip/hip_runtime.h>
#include <stdint.h>

#define VQ_N   131072   // rows = 32*64*64
#define VQ_D   64
#define VQ_K   512
#define NKT    32       // 512/16 k-tiles
#define NBLK   512      // 8 waves/block x 32 rows/wave = 256 rows/block

typedef __attribute__((ext_vector_type(8))) short  short8;   // 8 x bf16 bits
typedef __attribute__((ext_vector_type(4))) float  f32x4;

// ws float-offsets:
#define WS_HN    0        // 512 f:  32 + 0.5*||e_k||^2
#define WS_CBT   512      // 512*64 f: codebook, codeword-major cbt[k][d]
#define WS_FRAG  33280    // bf16x8 frag[32 kt][4 j][64 lane]; j: 0=eh d0,1=eh d1,2=el d0,3=el d1
#define WS_PART  66048    // NBLK f: per-block loss partials

__device__ __forceinline__ unsigned short f2bf(float f) {   // RNE f32->bf16 bits
    unsigned u = __float_as_uint(f);
    u += 0x7FFFu + ((u >> 16) & 1u);
    return (unsigned short)(u >> 16);
}
__device__ __forceinline__ float bf2f(unsigned short h) {
    return __uint_as_float(((unsigned)h) << 16);
}

// Build negated bf16 split of 8 floats: yh = bf16(-x), yl = bf16(-x - yh)
__device__ __forceinline__ void cvt8neg(float4 a, float4 b, short8& hi, short8& lo) {
    float f[8] = {a.x, a.y, a.z, a.w, b.x, b.y, b.z, b.w};
    union { short8 v; unsigned short u[8]; } H, L;
    #pragma unroll
    for (int e = 0; e < 8; ++e) {
        float y = -f[e];
        unsigned short h = f2bf(y);
        H.u[e] = h;
        L.u[e] = f2bf(y - bf2f(h));
    }
    hi = H.v; lo = L.v;
}

__device__ __forceinline__ bool lexlt(float s1, unsigned i1, float s2, unsigned i2) {
    return (s1 < s2) || ((s1 == s2) && (i1 < i2));
}

// ---------------- prep: codebook norms, fp32 transpose, bf16-split fragments ------
__global__ __launch_bounds__(64) void vq_prep(const float* __restrict__ enc,
                                              float* __restrict__ ws) {
    const int k  = blockIdx.x * 64 + threadIdx.x;   // 0..511
    const int kt = k >> 4, c = k & 15;
    float* cbt = ws + WS_CBT;
    unsigned short* frag = (unsigned short*)(ws + WS_FRAG);
    double hs = 0.0;
    for (int d = 0; d < VQ_D; ++d) {
        float v = enc[d * VQ_K + k];               // enc is [D][K]
        cbt[k * VQ_D + d] = v;
        hs += (double)v * (double)v;
        const int t = d >> 5, g = (d >> 3) & 3, e = d & 7;
        const int lane = 16 * g + c;
        unsigned short h = f2bf(v);
        frag[(((kt * 4) + t)     * 64 + lane) * 8 + e] = h;                 // eh
        frag[(((kt * 4) + 2 + t) * 64 + lane) * 8 + e] = f2bf(v - bf2f(h)); // el
    }
    ws[WS_HN + k] = 32.0f + 0.5f * (float)hs;
}

// ---------------- main: LDS-staged frags, MFMA screen + top-2 + f64 rescreen ------
__global__ __launch_bounds__(512) void vq_main(const float* __restrict__ x,
                                               const float* __restrict__ ws,
                                               float* __restrict__ out,
                                               float* __restrict__ partials) {
    const int tid = threadIdx.x;
    const int l   = tid & 63;          // lane
    const int wid = tid >> 6;          // wave in block (0..7)
    const int m   = l & 15;            // x-row within set (C col), frag spatial idx
    const int g   = l >> 4;            // k-group (d-slice / cand-quad group)
    const int rowbase = (blockIdx.x * 8 + wid) * 32;

    const float*  __restrict__ hn    = ws + WS_HN;
    const float*  __restrict__ cbt   = ws + WS_CBT;
    const short8* __restrict__ fragG = (const short8*)(ws + WS_FRAG);

    // Stage the whole frag table (128 KB) into LDS: 8192 short8, 512 threads -> 16 ea.
    __shared__ short8 fragLds[NKT * 4 * 64];
    #pragma unroll
    for (int i = 0; i < 16; ++i) {
        const int idx = i * 512 + tid;
        fragLds[idx] = fragG[idx];
    }

    // Two 16-row sets per wave; x kept exactly in regs for rescreen/loss.
    float4 xa0[2], xa1[2], xb0[2], xb1[2];
    short8 yh0[2], yl0[2], yh1[2], yl1[2];
    #pragma unroll
    for (int s = 0; s < 2; ++s) {
        const float* xr = x + (size_t)(rowbase + s * 16 + m) * VQ_D;
        xa0[s] = *(const float4*)(xr + 8 * g);
        xa1[s] = *(const float4*)(xr + 8 * g + 4);
        xb0[s] = *(const float4*)(xr + 32 + 8 * g);
        xb1[s] = *(const float4*)(xr + 32 + 8 * g + 4);
        cvt8neg(xa0[s], xa1[s], yh0[s], yl0[s]);
        cvt8neg(xb0[s], xb1[s], yh1[s], yl1[s]);
    }

    __syncthreads();   // frag table staged

    float    b1s[2] = {3.4e38f, 3.4e38f}, b2s[2] = {3.4e38f, 3.4e38f};
    unsigned b1i[2] = {0, 0},             b2i[2] = {0, 0};

    for (int kt = 0; kt < NKT; ++kt) {
        short8 f0 = fragLds[(kt * 4 + 0) * 64 + l];   // eh d-half0
        short8 f1 = fragLds[(kt * 4 + 1) * 64 + l];   // eh d-half1
        short8 f2 = fragLds[(kt * 4 + 2) * 64 + l];   // el d-half0
        short8 f3 = fragLds[(kt * 4 + 3) * 64 + l];   // el d-half1
        float4 h4 = *(const float4*)(hn + kt * 16 + 4 * g);
        const unsigned base = (unsigned)(kt * 16 + 4 * g);

        #pragma unroll
        for (int s = 0; s < 2; ++s) {
            f32x4 acc = {h4.x, h4.y, h4.z, h4.w};
            acc = __builtin_amdgcn_mfma_f32_16x16x32_bf16(f0, yh0[s], acc, 0, 0, 0);
            acc = __builtin_amdgcn_mfma_f32_16x16x32_bf16(f1, yh1[s], acc, 0, 0, 0);
            acc = __builtin_amdgcn_mfma_f32_16x16x32_bf16(f2, yh0[s], acc, 0, 0, 0);
            acc = __builtin_amdgcn_mfma_f32_16x16x32_bf16(f3, yh1[s], acc, 0, 0, 0);
            acc = __builtin_amdgcn_mfma_f32_16x16x32_bf16(f0, yl0[s], acc, 0, 0, 0);
            acc = __builtin_amdgcn_mfma_f32_16x16x32_bf16(f1, yl1[s], acc, 0, 0, 0);
            // acc[r] = score of cand base+r for x-row rowbase+s*16+m

            // quad top-2 (idx pref: lower r on ties)
            float a0 = acc[0], a1 = acc[1], a2 = acc[2], a3 = acc[3];
            bool c01 = a1 < a0;
            float lo01 = c01 ? a1 : a0, hi01 = c01 ? a0 : a1;
            unsigned i01 = c01 ? 1u : 0u;
            bool c23 = a3 < a2;
            float lo23 = c23 ? a3 : a2, hi23 = c23 ? a2 : a3;
            unsigned i23 = c23 ? 3u : 2u;
            bool cb = lo23 < lo01;
            float    q1  = cb ? lo23 : lo01;
            unsigned q1i = cb ? i23  : i01;
            float    u   = cb ? lo01 : lo23;
            unsigned ui  = cb ? i01  : i23;
            float    v   = cb ? hi23 : hi01;
            unsigned vi  = cb ? (i23 ^ 1u) : (i01 ^ 1u);
            // tie -> lower idx: cb: idx(u)<idx(v) use v<u;  !cb: idx(v)<idx(u) use !(u<v)
            bool takeV = cb ? (v < u) : !(u < v);
            float    q2  = takeV ? v  : u;
            unsigned q2i = takeV ? vi : ui;
            q1i += base; q2i += base;

            // merge into running top-2 (all new idx > all old idx; ties keep old)
            bool t1 = q1 < b1s[s];
            float    nu  = t1 ? b1s[s] : b2s[s];
            unsigned nui = t1 ? b1i[s] : b2i[s];
            float    nv  = t1 ? q2  : q1;
            unsigned nvi = t1 ? q2i : q1i;
            b1s[s] = t1 ? q1  : b1s[s];
            b1i[s] = t1 ? q1i : b1i[s];
            bool w = nv < nu;
            b2s[s] = w ? nv  : nu;
            b2i[s] = w ? nvi : nui;
        }
    }

    // butterfly allreduce of top-2 across the 4 k-groups (lanes sharing col m)
    #pragma unroll
    for (int st = 16; st <= 32; st <<= 1) {
        #pragma unroll
        for (int s = 0; s < 2; ++s) {
            float    o1s = __shfl_xor(b1s[s], st, 64);
            unsigned o1i = (unsigned)__shfl_xor((int)b1i[s], st, 64);
            float    o2s = __shfl_xor(b2s[s], st, 64);
            unsigned o2i = (unsigned)__shfl_xor((int)b2i[s], st, 64);
            bool c = lexlt(o1s, o1i, b1s[s], b1i[s]);
            float    n1s = c ? o1s : b1s[s];
            unsigned n1i = c ? o1i : b1i[s];
            float    lss = c ? b1s[s] : o1s;     // loser of the firsts
            unsigned lsi = c ? b1i[s] : o1i;
            bool c2 = lexlt(b2s[s], b2i[s], o2s, o2i);
            float    m2s = c2 ? b2s[s] : o2s;
            unsigned m2i = c2 ? b2i[s] : o2i;
            bool c3 = lexlt(lss, lsi, m2s, m2i);
            b1s[s] = n1s; b1i[s] = n1i;
            b2s[s] = c3 ? lss : m2s;
            b2i[s] = c3 ? lsi : m2i;
        }
    }

    // rescreen + write + loss, per set
    float ls = 0.f;
    #pragma unroll
    for (int s = 0; s < 2; ++s) {
        const unsigned i1 = b1i[s], i2 = b2i[s];
        const float* e1p = cbt + (size_t)i1 * VQ_D;
        const float* e2p = cbt + (size_t)i2 * VQ_D;
        float4 p10 = *(const float4*)(e1p + 8 * g);
        float4 p11 = *(const float4*)(e1p + 8 * g + 4);
        float4 p12 = *(const float4*)(e1p + 32 + 8 * g);
        float4 p13 = *(const float4*)(e1p + 32 + 8 * g + 4);
        float4 p20 = *(const float4*)(e2p + 8 * g);
        float4 p21 = *(const float4*)(e2p + 8 * g + 4);
        float4 p22 = *(const float4*)(e2p + 32 + 8 * g);
        float4 p23 = *(const float4*)(e2p + 32 + 8 * g + 4);

        double dd1 = 0.0, dd2 = 0.0;
        {
            const float xs[16] = {xa0[s].x,xa0[s].y,xa0[s].z,xa0[s].w,
                                  xa1[s].x,xa1[s].y,xa1[s].z,xa1[s].w,
                                  xb0[s].x,xb0[s].y,xb0[s].z,xb0[s].w,
                                  xb1[s].x,xb1[s].y,xb1[s].z,xb1[s].w};
            const float q1v[16] = {p10.x,p10.y,p10.z,p10.w, p11.x,p11.y,p11.z,p11.w,
                                   p12.x,p12.y,p12.z,p12.w, p13.x,p13.y,p13.z,p13.w};
            const float q2v[16] = {p20.x,p20.y,p20.z,p20.w, p21.x,p21.y,p21.z,p21.w,
                                   p22.x,p22.y,p22.z,p22.w, p23.x,p23.y,p23.z,p23.w};
            #pragma unroll
            for (int j = 0; j < 16; ++j) {
                double u1 = (double)xs[j] - (double)q1v[j];
                double u2 = (double)xs[j] - (double)q2v[j];
                dd1 = fma(u1, u1, dd1);
                dd2 = fma(u2, u2, dd2);
            }
        }
        dd1 += __shfl_xor(dd1, 16, 64);  dd1 += __shfl_xor(dd1, 32, 64);
        dd2 += __shfl_xor(dd2, 16, 64);  dd2 += __shfl_xor(dd2, 32, 64);
        const bool take1 = (dd1 < dd2) || ((dd1 == dd2) && (i1 < i2));

        float4 q0, q1o, q2o, q3o;
        q0.x  = take1 ? p10.x : p20.x; q0.y  = take1 ? p10.y : p20.y;
        q0.z  = take1 ? p10.z : p20.z; q0.w  = take1 ? p10.w : p20.w;
        q1o.x = take1 ? p11.x : p21.x; q1o.y = take1 ? p11.y : p21.y;
        q1o.z = take1 ? p11.z : p21.z; q1o.w = take1 ? p11.w : p21.w;
        q2o.x = take1 ? p12.x : p22.x; q2o.y = take1 ? p12.y : p22.y;
        q2o.z = take1 ? p12.z : p22.z; q2o.w = take1 ? p12.w : p22.w;
        q3o.x = take1 ? p13.x : p23.x; q3o.y = take1 ? p13.y : p23.y;
        q3o.z = take1 ? p13.z : p23.z; q3o.w = take1 ? p13.w : p23.w;

        float* orow = out + (size_t)(rowbase + s * 16 + m) * VQ_D;
        *(float4*)(orow + 8 * g)          = q0;
        *(float4*)(orow + 8 * g + 4)      = q1o;
        *(float4*)(orow + 32 + 8 * g)     = q2o;
        *(float4*)(orow + 32 + 8 * g + 4) = q3o;

        float d;
        d = q0.x  - xa0[s].x; ls = fmaf(d, d, ls);  d = q0.y  - xa0[s].y; ls = fmaf(d, d, ls);
        d = q0.z  - xa0[s].z; ls = fmaf(d, d, ls);  d = q0.w  - xa0[s].w; ls = fmaf(d, d, ls);
        d = q1o.x - xa1[s].x; ls = fmaf(d, d, ls);  d = q1o.y - xa1[s].y; ls = fmaf(d, d, ls);
        d = q1o.z - xa1[s].z; ls = fmaf(d, d, ls);  d = q1o.w - xa1[s].w; ls = fmaf(d, d, ls);
        d = q2o.x - xb0[s].x; ls = fmaf(d, d, ls);  d = q2o.y - xb0[s].y; ls = fmaf(d, d, ls);
        d = q2o.z - xb0[s].z; ls = fmaf(d, d, ls);  d = q2o.w - xb0[s].w; ls = fmaf(d, d, ls);
        d = q3o.x - xb1[s].x; ls = fmaf(d, d, ls);  d = q3o.y - xb1[s].y; ls = fmaf(d, d, ls);
        d = q3o.z - xb1[s].z; ls = fmaf(d, d, ls);  d = q3o.w - xb1[s].w; ls = fmaf(d, d, ls);
    }

    #pragma unroll
    for (int off = 32; off > 0; off >>= 1) ls += __shfl_xor(ls, off, 64);

    __shared__ float lsw[8];
    if ((tid & 63) == 0) lsw[wid] = ls;
    __syncthreads();
    if (tid == 0) {
        float t = 0.f;
        #pragma unroll
        for (int wv = 0; wv < 8; ++wv) t += lsw[wv];
        partials[blockIdx.x] = t;
    }
}

// ---------------- finalize: deterministic partial-sum + scale ---------------------
__global__ __launch_bounds__(256) void vq_fin(const float* __restrict__ partials,
                                              float* __restrict__ out) {
    const int tid = threadIdx.x;
    float s = 0.f;
    #pragma unroll
    for (int j = 0; j < NBLK / 256; ++j) s += partials[tid + 256 * j];
    #pragma unroll
    for (int off = 32; off > 0; off >>= 1) s += __shfl_xor(s, off, 64);
    __shared__ float w[4];
    if ((tid & 63) == 0) w[tid >> 6] = s;
    __syncthreads();
    if (tid == 0)
        out[(size_t)VQ_N * VQ_D] = 1.25f * (w[0] + w[1] + w[2] + w[3]) / 8388608.0f;
}

extern "C" void kernel_launch(void* const* d_in, const int* in_sizes, int n_in,
                              void* d_out, int out_size, void* d_ws, size_t ws_size,
                              hipStream_t stream) {
    const float* x   = (const float*)d_in[0];   // (32,64,64,64) fp32
    const float* enc = (const float*)d_in[1];   // (64,512) fp32
    float* out = (float*)d_out;                 // 8388608 quantised + 1 loss
    float* ws  = (float*)d_ws;

    vq_prep<<<8, 64, 0, stream>>>(enc, ws);
    vq_main<<<NBLK, 512, 0, stream>>>(x, ws, out, ws + WS_PART);
    vq_fin<<<1, 256, 0, stream>>>(ws + WS_PART, out);
}

// Round 7
// 60.655 us; speedup vs baseline: 1.1655x; 1.1655x over previous
//
#include <hip/hip_runtime.h>
#include <stdint.h>

#define VQ_N   131072   // rows = 32*64*64
#define VQ_D   64
#define VQ_K   512
#define NKT    32       // 512/16 k-tiles
#define NBLK   256      // 16 waves/block x 32 rows/wave = 512 rows/block

typedef __attribute__((ext_vector_type(8))) short  short8;   // 8 x bf16 bits
typedef __attribute__((ext_vector_type(4))) float  f32x4;

// ws float-offsets:
#define WS_HN    0        // 512 f:  32 + 0.5*||e_k||^2
#define WS_CBT   512      // 512*64 f: codebook, codeword-major cbt[k][d]
#define WS_FRAG  33280    // bf16x8 frag[32 kt][4 j][64 lane]; j: 0=eh d0,1=eh d1,2=el d0,3=el d1
#define WS_PART  66048    // NBLK f: per-block loss partials

__device__ __forceinline__ unsigned short f2bf(float f) {   // RNE f32->bf16 bits
    unsigned u = __float_as_uint(f);
    u += 0x7FFFu + ((u >> 16) & 1u);
    return (unsigned short)(u >> 16);
}
__device__ __forceinline__ float bf2f(unsigned short h) {
    return __uint_as_float(((unsigned)h) << 16);
}

// Build negated bf16 split of 8 floats: yh = bf16(-x), yl = bf16(-x - yh)
__device__ __forceinline__ void cvt8neg(float4 a, float4 b, short8& hi, short8& lo) {
    float f[8] = {a.x, a.y, a.z, a.w, b.x, b.y, b.z, b.w};
    union { short8 v; unsigned short u[8]; } H, L;
    #pragma unroll
    for (int e = 0; e < 8; ++e) {
        float y = -f[e];
        unsigned short h = f2bf(y);
        H.u[e] = h;
        L.u[e] = f2bf(y - bf2f(h));
    }
    hi = H.v; lo = L.v;
}

__device__ __forceinline__ bool lexlt(float s1, unsigned i1, float s2, unsigned i2) {
    return (s1 < s2) || ((s1 == s2) && (i1 < i2));
}

// ---------------- prep: codebook norms, fp32 transpose, bf16-split fragments ------
__global__ __launch_bounds__(64) void vq_prep(const float* __restrict__ enc,
                                              float* __restrict__ ws) {
    const int k  = blockIdx.x * 64 + threadIdx.x;   // 0..511
    const int kt = k >> 4, c = k & 15;
    float* cbt = ws + WS_CBT;
    unsigned short* frag = (unsigned short*)(ws + WS_FRAG);
    double hs = 0.0;
    for (int d = 0; d < VQ_D; ++d) {
        float v = enc[d * VQ_K + k];               // enc is [D][K]
        cbt[k * VQ_D + d] = v;
        hs += (double)v * (double)v;
        const int t = d >> 5, g = (d >> 3) & 3, e = d & 7;
        const int lane = 16 * g + c;
        unsigned short h = f2bf(v);
        frag[(((kt * 4) + t)     * 64 + lane) * 8 + e] = h;                 // eh
        frag[(((kt * 4) + 2 + t) * 64 + lane) * 8 + e] = f2bf(v - bf2f(h)); // el
    }
    ws[WS_HN + k] = 32.0f + 0.5f * (float)hs;
}

// ---------------- main: LDS frags+hn, 16 waves/block, prefetch pipeline -----------
__global__ __launch_bounds__(1024) void vq_main(const float* __restrict__ x,
                                                const float* __restrict__ ws,
                                                float* __restrict__ out,
                                                float* __restrict__ partials) {
    const int tid = threadIdx.x;
    const int l   = tid & 63;          // lane
    const int wid = tid >> 6;          // wave in block (0..15)
    const int m   = l & 15;            // x-row within set (C col), frag spatial idx
    const int g   = l >> 4;            // k-group (d-slice / cand-quad group)
    const int rowbase = (blockIdx.x * 16 + wid) * 32;

    const float*  __restrict__ hnG   = ws + WS_HN;
    const float*  __restrict__ cbt   = ws + WS_CBT;
    const short8* __restrict__ fragG = (const short8*)(ws + WS_FRAG);

    // Stage frag table (128 KB) + hn (2 KB) into LDS.
    __shared__ short8 fragLds[NKT * 4 * 64];
    __shared__ float  hnLds[VQ_K];
    #pragma unroll
    for (int i = 0; i < 8; ++i) {
        const int idx = i * 1024 + tid;
        fragLds[idx] = fragG[idx];
    }
    if (tid < VQ_K) hnLds[tid] = hnG[tid];

    // Build bf16-split of the two 16-row sets; exact x NOT kept (reloaded in epilogue).
    short8 yh0[2], yl0[2], yh1[2], yl1[2];
    #pragma unroll
    for (int s = 0; s < 2; ++s) {
        const float* xr = x + (size_t)(rowbase + s * 16 + m) * VQ_D;
        float4 a0 = *(const float4*)(xr + 8 * g);
        float4 a1 = *(const float4*)(xr + 8 * g + 4);
        float4 b0 = *(const float4*)(xr + 32 + 8 * g);
        float4 b1 = *(const float4*)(xr + 32 + 8 * g + 4);
        cvt8neg(a0, a1, yh0[s], yl0[s]);
        cvt8neg(b0, b1, yh1[s], yl1[s]);
    }

    __syncthreads();   // staging complete

    float    b1s[2] = {3.4e38f, 3.4e38f}, b2s[2] = {3.4e38f, 3.4e38f};
    unsigned b1i[2] = {0, 0},             b2i[2] = {0, 0};

    // software-pipelined k-loop: prefetch kt+1 frags+hn while computing kt
    short8 f0 = fragLds[0 * 64 + l];
    short8 f1 = fragLds[1 * 64 + l];
    short8 f2 = fragLds[2 * 64 + l];
    short8 f3 = fragLds[3 * 64 + l];
    float4 h4 = *(const float4*)(hnLds + 4 * g);

    for (int kt = 0; kt < NKT; ++kt) {
        const int nkt = (kt + 1) & 31;   // wrap on last iter (values unused)
        short8 nf0 = fragLds[(nkt * 4 + 0) * 64 + l];
        short8 nf1 = fragLds[(nkt * 4 + 1) * 64 + l];
        short8 nf2 = fragLds[(nkt * 4 + 2) * 64 + l];
        short8 nf3 = fragLds[(nkt * 4 + 3) * 64 + l];
        float4 nh4 = *(const float4*)(hnLds + nkt * 16 + 4 * g);

        const unsigned base = (unsigned)(kt * 16 + 4 * g);
        #pragma unroll
        for (int s = 0; s < 2; ++s) {
            f32x4 acc = {h4.x, h4.y, h4.z, h4.w};
            acc = __builtin_amdgcn_mfma_f32_16x16x32_bf16(f0, yh0[s], acc, 0, 0, 0);
            acc = __builtin_amdgcn_mfma_f32_16x16x32_bf16(f1, yh1[s], acc, 0, 0, 0);
            acc = __builtin_amdgcn_mfma_f32_16x16x32_bf16(f2, yh0[s], acc, 0, 0, 0);
            acc = __builtin_amdgcn_mfma_f32_16x16x32_bf16(f3, yh1[s], acc, 0, 0, 0);
            acc = __builtin_amdgcn_mfma_f32_16x16x32_bf16(f0, yl0[s], acc, 0, 0, 0);
            acc = __builtin_amdgcn_mfma_f32_16x16x32_bf16(f1, yl1[s], acc, 0, 0, 0);
            // acc[r] = score of cand base+r for x-row rowbase+s*16+m

            // quad top-2 (idx pref: lower r on ties)
            float a0 = acc[0], a1 = acc[1], a2 = acc[2], a3 = acc[3];
            bool c01 = a1 < a0;
            float lo01 = c01 ? a1 : a0, hi01 = c01 ? a0 : a1;
            unsigned i01 = c01 ? 1u : 0u;
            bool c23 = a3 < a2;
            float lo23 = c23 ? a3 : a2, hi23 = c23 ? a2 : a3;
            unsigned i23 = c23 ? 3u : 2u;
            bool cb = lo23 < lo01;
            float    q1  = cb ? lo23 : lo01;
            unsigned q1i = cb ? i23  : i01;
            float    u   = cb ? lo01 : lo23;
            unsigned ui  = cb ? i01  : i23;
            float    v   = cb ? hi23 : hi01;
            unsigned vi  = cb ? (i23 ^ 1u) : (i01 ^ 1u);
            // tie -> lower idx: cb: idx(u)<idx(v) use v<u;  !cb: idx(v)<idx(u) use !(u<v)
            bool takeV = cb ? (v < u) : !(u < v);
            float    q2  = takeV ? v  : u;
            unsigned q2i = takeV ? vi : ui;
            q1i += base; q2i += base;

            // merge into running top-2 (all new idx > all old idx; ties keep old)
            bool t1 = q1 < b1s[s];
            float    nu  = t1 ? b1s[s] : b2s[s];
            unsigned nui = t1 ? b1i[s] : b2i[s];
            float    nv  = t1 ? q2  : q1;
            unsigned nvi = t1 ? q2i : q1i;
            b1s[s] = t1 ? q1  : b1s[s];
            b1i[s] = t1 ? q1i : b1i[s];
            bool w = nv < nu;
            b2s[s] = w ? nv  : nu;
            b2i[s] = w ? nvi : nui;
        }
        f0 = nf0; f1 = nf1; f2 = nf2; f3 = nf3; h4 = nh4;
    }

    // butterfly allreduce of top-2 across the 4 k-groups (lanes sharing col m)
    #pragma unroll
    for (int st = 16; st <= 32; st <<= 1) {
        #pragma unroll
        for (int s = 0; s < 2; ++s) {
            float    o1s = __shfl_xor(b1s[s], st, 64);
            unsigned o1i = (unsigned)__shfl_xor((int)b1i[s], st, 64);
            float    o2s = __shfl_xor(b2s[s], st, 64);
            unsigned o2i = (unsigned)__shfl_xor((int)b2i[s], st, 64);
            bool c = lexlt(o1s, o1i, b1s[s], b1i[s]);
            float    n1s = c ? o1s : b1s[s];
            unsigned n1i = c ? o1i : b1i[s];
            float    lss = c ? b1s[s] : o1s;     // loser of the firsts
            unsigned lsi = c ? b1i[s] : o1i;
            bool c2 = lexlt(b2s[s], b2i[s], o2s, o2i);
            float    m2s = c2 ? b2s[s] : o2s;
            unsigned m2i = c2 ? b2i[s] : o2i;
            bool c3 = lexlt(lss, lsi, m2s, m2i);
            b1s[s] = n1s; b1i[s] = n1i;
            b2s[s] = c3 ? lss : m2s;
            b2i[s] = c3 ? lsi : m2i;
        }
    }

    // rescreen + write + loss, per set (x reloaded exactly from global)
    float ls = 0.f;
    #pragma unroll
    for (int s = 0; s < 2; ++s) {
        const unsigned i1 = b1i[s], i2 = b2i[s];
        const float* xr = x + (size_t)(rowbase + s * 16 + m) * VQ_D;
        float4 xa0 = *(const float4*)(xr + 8 * g);
        float4 xa1 = *(const float4*)(xr + 8 * g + 4);
        float4 xb0 = *(const float4*)(xr + 32 + 8 * g);
        float4 xb1 = *(const float4*)(xr + 32 + 8 * g + 4);

        const float* e1p = cbt + (size_t)i1 * VQ_D;
        const float* e2p = cbt + (size_t)i2 * VQ_D;
        float4 p10 = *(const float4*)(e1p + 8 * g);
        float4 p11 = *(const float4*)(e1p + 8 * g + 4);
        float4 p12 = *(const float4*)(e1p + 32 + 8 * g);
        float4 p13 = *(const float4*)(e1p + 32 + 8 * g + 4);
        float4 p20 = *(const float4*)(e2p + 8 * g);
        float4 p21 = *(const float4*)(e2p + 8 * g + 4);
        float4 p22 = *(const float4*)(e2p + 32 + 8 * g);
        float4 p23 = *(const float4*)(e2p + 32 + 8 * g + 4);

        double dd1 = 0.0, dd2 = 0.0;
        {
            const float xs[16] = {xa0.x,xa0.y,xa0.z,xa0.w, xa1.x,xa1.y,xa1.z,xa1.w,
                                  xb0.x,xb0.y,xb0.z,xb0.w, xb1.x,xb1.y,xb1.z,xb1.w};
            const float q1v[16] = {p10.x,p10.y,p10.z,p10.w, p11.x,p11.y,p11.z,p11.w,
                                   p12.x,p12.y,p12.z,p12.w, p13.x,p13.y,p13.z,p13.w};
            const float q2v[16] = {p20.x,p20.y,p20.z,p20.w, p21.x,p21.y,p21.z,p21.w,
                                   p22.x,p22.y,p22.z,p22.w, p23.x,p23.y,p23.z,p23.w};
            #pragma unroll
            for (int j = 0; j < 16; ++j) {
                double u1 = (double)xs[j] - (double)q1v[j];
                double u2 = (double)xs[j] - (double)q2v[j];
                dd1 = fma(u1, u1, dd1);
                dd2 = fma(u2, u2, dd2);
            }
        }
        dd1 += __shfl_xor(dd1, 16, 64);  dd1 += __shfl_xor(dd1, 32, 64);
        dd2 += __shfl_xor(dd2, 16, 64);  dd2 += __shfl_xor(dd2, 32, 64);
        const bool take1 = (dd1 < dd2) || ((dd1 == dd2) && (i1 < i2));

        float4 q0, q1o, q2o, q3o;
        q0.x  = take1 ? p10.x : p20.x; q0.y  = take1 ? p10.y : p20.y;
        q0.z  = take1 ? p10.z : p20.z; q0.w  = take1 ? p10.w : p20.w;
        q1o.x = take1 ? p11.x : p21.x; q1o.y = take1 ? p11.y : p21.y;
        q1o.z = take1 ? p11.z : p21.z; q1o.w = take1 ? p11.w : p21.w;
        q2o.x = take1 ? p12.x : p22.x; q2o.y = take1 ? p12.y : p22.y;
        q2o.z = take1 ? p12.z : p22.z; q2o.w = take1 ? p12.w : p22.w;
        q3o.x = take1 ? p13.x : p23.x; q3o.y = take1 ? p13.y : p23.y;
        q3o.z = take1 ? p13.z : p23.z; q3o.w = take1 ? p13.w : p23.w;

        float* orow = out + (size_t)(rowbase + s * 16 + m) * VQ_D;
        *(float4*)(orow + 8 * g)          = q0;
        *(float4*)(orow + 8 * g + 4)      = q1o;
        *(float4*)(orow + 32 + 8 * g)     = q2o;
        *(float4*)(orow + 32 + 8 * g + 4) = q3o;

        float d;
        d = q0.x  - xa0.x; ls = fmaf(d, d, ls);  d = q0.y  - xa0.y; ls = fmaf(d, d, ls);
        d = q0.z  - xa0.z; ls = fmaf(d, d, ls);  d = q0.w  - xa0.w; ls = fmaf(d, d, ls);
        d = q1o.x - xa1.x; ls = fmaf(d, d, ls);  d = q1o.y - xa1.y; ls = fmaf(d, d, ls);
        d = q1o.z - xa1.z; ls = fmaf(d, d, ls);  d = q1o.w - xa1.w; ls = fmaf(d, d, ls);
        d = q2o.x - xb0.x; ls = fmaf(d, d, ls);  d = q2o.y - xb0.y; ls = fmaf(d, d, ls);
        d = q2o.z - xb0.z; ls = fmaf(d, d, ls);  d = q2o.w - xb0.w; ls = fmaf(d, d, ls);
        d = q3o.x - xb1.x; ls = fmaf(d, d, ls);  d = q3o.y - xb1.y; ls = fmaf(d, d, ls);
        d = q3o.z - xb1.z; ls = fmaf(d, d, ls);  d = q3o.w - xb1.w; ls = fmaf(d, d, ls);
    }

    #pragma unroll
    for (int off = 32; off > 0; off >>= 1) ls += __shfl_xor(ls, off, 64);

    __shared__ float lsw[16];
    if ((tid & 63) == 0) lsw[wid] = ls;
    __syncthreads();
    if (tid == 0) {
        float t = 0.f;
        #pragma unroll
        for (int wv = 0; wv < 16; ++wv) t += lsw[wv];
        partials[blockIdx.x] = t;
    }
}

// ---------------- finalize: deterministic partial-sum + scale ---------------------
__global__ __launch_bounds__(256) void vq_fin(const float* __restrict__ partials,
                                              float* __restrict__ out) {
    const int tid = threadIdx.x;
    float s = 0.f;
    #pragma unroll
    for (int j = 0; j < NBLK / 256; ++j) s += partials[tid + 256 * j];
    #pragma unroll
    for (int off = 32; off > 0; off >>= 1) s += __shfl_xor(s, off, 64);
    __shared__ float w[4];
    if ((tid & 63) == 0) w[tid >> 6] = s;
    __syncthreads();
    if (tid == 0)
        out[(size_t)VQ_N * VQ_D] = 1.25f * (w[0] + w[1] + w[2] + w[3]) / 8388608.0f;
}

extern "C" void kernel_launch(void* const* d_in, const int* in_sizes, int n_in,
                              void* d_out, int out_size, void* d_ws, size_t ws_size,
                              hipStream_t stream) {
    const float* x   = (const float*)d_in[0];   // (32,64,64,64) fp32
    const float* enc = (const float*)d_in[1];   // (64,512) fp32
    float* out = (float*)d_out;                 // 8388608 quantised + 1 loss
    float* ws  = (float*)d_ws;

    vq_prep<<<8, 64, 0, stream>>>(enc, ws);
    vq_main<<<NBLK, 1024, 0, stream>>>(x, ws, out, ws + WS_PART);
    vq_fin<<<1, 256, 0, stream>>>(ws + WS_PART, out);
}

// Round 8
// 59.418 us; speedup vs baseline: 1.1898x; 1.0208x over previous
//
#include <hip/hip_runtime.h>
#include <stdint.h>

#define VQ_N   131072   // rows = 32*64*64
#define VQ_D   64
#define VQ_K   512
#define NKT    32       // 512/16 k-tiles
#define NBLK   256      // 16 waves/block x 32 rows/wave = 512 rows/block

typedef __attribute__((ext_vector_type(8))) short  short8;   // 8 x bf16 bits
typedef __attribute__((ext_vector_type(4))) float  f32x4;

// ws float-offsets:
#define WS_HN    0        // 512 f:  32 + 0.5*||e_k||^2
#define WS_CBT   512      // 512*64 f: codebook, codeword-major cbt[k][d]
#define WS_FRAG  33280    // bf16x8 frag[32 kt][4 j][64 lane]; j: 0=eh d0,1=eh d1,2=el d0,3=el d1
#define WS_PART  66048    // NBLK f: per-block loss partials

__device__ __forceinline__ unsigned short f2bf(float f) {   // RNE f32->bf16 bits
    unsigned u = __float_as_uint(f);
    u += 0x7FFFu + ((u >> 16) & 1u);
    return (unsigned short)(u >> 16);
}
__device__ __forceinline__ float bf2f(unsigned short h) {
    return __uint_as_float(((unsigned)h) << 16);
}

// Build negated bf16 split of 8 floats: yh = bf16(-x), yl = bf16(-x - yh)
__device__ __forceinline__ void cvt8neg(float4 a, float4 b, short8& hi, short8& lo) {
    float f[8] = {a.x, a.y, a.z, a.w, b.x, b.y, b.z, b.w};
    union { short8 v; unsigned short u[8]; } H, L;
    #pragma unroll
    for (int e = 0; e < 8; ++e) {
        float y = -f[e];
        unsigned short h = f2bf(y);
        H.u[e] = h;
        L.u[e] = f2bf(y - bf2f(h));
    }
    hi = H.v; lo = L.v;
}

__device__ __forceinline__ bool lexlt(float s1, unsigned i1, float s2, unsigned i2) {
    return (s1 < s2) || ((s1 == s2) && (i1 < i2));
}

// ---------------- prep: codebook norms, fp32 transpose, bf16-split fragments ------
__global__ __launch_bounds__(64) void vq_prep(const float* __restrict__ enc,
                                              float* __restrict__ ws) {
    const int k  = blockIdx.x * 64 + threadIdx.x;   // 0..511
    const int kt = k >> 4, c = k & 15;
    float* cbt = ws + WS_CBT;
    unsigned short* frag = (unsigned short*)(ws + WS_FRAG);
    double hs = 0.0;
    for (int d = 0; d < VQ_D; ++d) {
        float v = enc[d * VQ_K + k];               // enc is [D][K]
        cbt[k * VQ_D + d] = v;
        hs += (double)v * (double)v;
        const int t = d >> 5, g = (d >> 3) & 3, e = d & 7;
        const int lane = 16 * g + c;
        unsigned short h = f2bf(v);
        frag[(((kt * 4) + t)     * 64 + lane) * 8 + e] = h;                 // eh
        frag[(((kt * 4) + 2 + t) * 64 + lane) * 8 + e] = f2bf(v - bf2f(h)); // el
    }
    ws[WS_HN + k] = 32.0f + 0.5f * (float)hs;
}

// ---------------- main: LDS frags+hn, 16 waves/block @ 4 waves/EU -----------------
__global__ __launch_bounds__(1024, 4) void vq_main(const float* __restrict__ x,
                                                   const float* __restrict__ ws,
                                                   float* __restrict__ out,
                                                   float* __restrict__ partials) {
    const int tid = threadIdx.x;
    const int l   = tid & 63;          // lane
    const int wid = tid >> 6;          // wave in block (0..15)
    const int m   = l & 15;            // x-row within set (C col), frag spatial idx
    const int g   = l >> 4;            // k-group (d-slice / cand-quad group)
    const int rowbase = (blockIdx.x * 16 + wid) * 32;

    const float*  __restrict__ hnG   = ws + WS_HN;
    const float*  __restrict__ cbt   = ws + WS_CBT;
    const short8* __restrict__ fragG = (const short8*)(ws + WS_FRAG);

    // Stage frag table (128 KB) + hn (2 KB) into LDS.
    __shared__ short8 fragLds[NKT * 4 * 64];
    __shared__ float  hnLds[VQ_K];
    #pragma unroll
    for (int i = 0; i < 8; ++i) {
        const int idx = i * 1024 + tid;
        fragLds[idx] = fragG[idx];
    }
    if (tid < VQ_K) hnLds[tid] = hnG[tid];

    // Two 16-row sets per wave; exact x KEPT in regs for rescreen/loss.
    float4 xa0[2], xa1[2], xb0[2], xb1[2];
    short8 yh0[2], yl0[2], yh1[2], yl1[2];
    #pragma unroll
    for (int s = 0; s < 2; ++s) {
        const float* xr = x + (size_t)(rowbase + s * 16 + m) * VQ_D;
        xa0[s] = *(const float4*)(xr + 8 * g);
        xa1[s] = *(const float4*)(xr + 8 * g + 4);
        xb0[s] = *(const float4*)(xr + 32 + 8 * g);
        xb1[s] = *(const float4*)(xr + 32 + 8 * g + 4);
        cvt8neg(xa0[s], xa1[s], yh0[s], yl0[s]);
        cvt8neg(xb0[s], xb1[s], yh1[s], yl1[s]);
    }

    __syncthreads();   // staging complete

    float    b1s[2] = {3.4e38f, 3.4e38f}, b2s[2] = {3.4e38f, 3.4e38f};
    unsigned b1i[2] = {0, 0},             b2i[2] = {0, 0};

    for (int kt = 0; kt < NKT; ++kt) {
        short8 f0 = fragLds[kt * 256 +   0 + l];   // eh d-half0
        short8 f1 = fragLds[kt * 256 +  64 + l];   // eh d-half1
        short8 f2 = fragLds[kt * 256 + 128 + l];   // el d-half0
        short8 f3 = fragLds[kt * 256 + 192 + l];   // el d-half1
        float4 h4 = *(const float4*)(hnLds + kt * 16 + 4 * g);
        const unsigned base = (unsigned)(kt * 16 + 4 * g);

        #pragma unroll
        for (int s = 0; s < 2; ++s) {
            f32x4 acc = {h4.x, h4.y, h4.z, h4.w};
            acc = __builtin_amdgcn_mfma_f32_16x16x32_bf16(f0, yh0[s], acc, 0, 0, 0);
            acc = __builtin_amdgcn_mfma_f32_16x16x32_bf16(f1, yh1[s], acc, 0, 0, 0);
            acc = __builtin_amdgcn_mfma_f32_16x16x32_bf16(f2, yh0[s], acc, 0, 0, 0);
            acc = __builtin_amdgcn_mfma_f32_16x16x32_bf16(f3, yh1[s], acc, 0, 0, 0);
            acc = __builtin_amdgcn_mfma_f32_16x16x32_bf16(f0, yl0[s], acc, 0, 0, 0);
            acc = __builtin_amdgcn_mfma_f32_16x16x32_bf16(f1, yl1[s], acc, 0, 0, 0);
            // acc[r] = score of cand base+r for x-row rowbase+s*16+m

            // quad top-2 (idx pref: lower r on ties)
            float a0 = acc[0], a1 = acc[1], a2 = acc[2], a3 = acc[3];
            bool c01 = a1 < a0;
            float lo01 = c01 ? a1 : a0, hi01 = c01 ? a0 : a1;
            unsigned i01 = c01 ? 1u : 0u;
            bool c23 = a3 < a2;
            float lo23 = c23 ? a3 : a2, hi23 = c23 ? a2 : a3;
            unsigned i23 = c23 ? 3u : 2u;
            bool cb = lo23 < lo01;
            float    q1  = cb ? lo23 : lo01;
            unsigned q1i = cb ? i23  : i01;
            float    u   = cb ? lo01 : lo23;
            unsigned ui  = cb ? i01  : i23;
            float    v   = cb ? hi23 : hi01;
            unsigned vi  = cb ? (i23 ^ 1u) : (i01 ^ 1u);
            // tie -> lower idx: cb: idx(u)<idx(v) use v<u;  !cb: idx(v)<idx(u) use !(u<v)
            bool takeV = cb ? (v < u) : !(u < v);
            float    q2  = takeV ? v  : u;
            unsigned q2i = takeV ? vi : ui;
            q1i += base; q2i += base;

            // merge into running top-2 (all new idx > all old idx; ties keep old)
            bool t1 = q1 < b1s[s];
            float    nu  = t1 ? b1s[s] : b2s[s];
            unsigned nui = t1 ? b1i[s] : b2i[s];
            float    nv  = t1 ? q2  : q1;
            unsigned nvi = t1 ? q2i : q1i;
            b1s[s] = t1 ? q1  : b1s[s];
            b1i[s] = t1 ? q1i : b1i[s];
            bool w = nv < nu;
            b2s[s] = w ? nv  : nu;
            b2i[s] = w ? nvi : nui;
        }
    }

    // butterfly allreduce of top-2 across the 4 k-groups (lanes sharing col m)
    #pragma unroll
    for (int st = 16; st <= 32; st <<= 1) {
        #pragma unroll
        for (int s = 0; s < 2; ++s) {
            float    o1s = __shfl_xor(b1s[s], st, 64);
            unsigned o1i = (unsigned)__shfl_xor((int)b1i[s], st, 64);
            float    o2s = __shfl_xor(b2s[s], st, 64);
            unsigned o2i = (unsigned)__shfl_xor((int)b2i[s], st, 64);
            bool c = lexlt(o1s, o1i, b1s[s], b1i[s]);
            float    n1s = c ? o1s : b1s[s];
            unsigned n1i = c ? o1i : b1i[s];
            float    lss = c ? b1s[s] : o1s;     // loser of the firsts
            unsigned lsi = c ? b1i[s] : o1i;
            bool c2 = lexlt(b2s[s], b2i[s], o2s, o2i);
            float    m2s = c2 ? b2s[s] : o2s;
            unsigned m2i = c2 ? b2i[s] : o2i;
            bool c3 = lexlt(lss, lsi, m2s, m2i);
            b1s[s] = n1s; b1i[s] = n1i;
            b2s[s] = c3 ? lss : m2s;
            b2i[s] = c3 ? lsi : m2i;
        }
    }

    // rescreen + write + loss, per set (x still in regs)
    float ls = 0.f;
    #pragma unroll
    for (int s = 0; s < 2; ++s) {
        const unsigned i1 = b1i[s], i2 = b2i[s];
        const float* e1p = cbt + (size_t)i1 * VQ_D;
        const float* e2p = cbt + (size_t)i2 * VQ_D;
        float4 p10 = *(const float4*)(e1p + 8 * g);
        float4 p11 = *(const float4*)(e1p + 8 * g + 4);
        float4 p12 = *(const float4*)(e1p + 32 + 8 * g);
        float4 p13 = *(const float4*)(e1p + 32 + 8 * g + 4);
        float4 p20 = *(const float4*)(e2p + 8 * g);
        float4 p21 = *(const float4*)(e2p + 8 * g + 4);
        float4 p22 = *(const float4*)(e2p + 32 + 8 * g);
        float4 p23 = *(const float4*)(e2p + 32 + 8 * g + 4);

        double dd1 = 0.0, dd2 = 0.0;
        {
            const float xs[16] = {xa0[s].x,xa0[s].y,xa0[s].z,xa0[s].w,
                                  xa1[s].x,xa1[s].y,xa1[s].z,xa1[s].w,
                                  xb0[s].x,xb0[s].y,xb0[s].z,xb0[s].w,
                                  xb1[s].x,xb1[s].y,xb1[s].z,xb1[s].w};
            const float q1v[16] = {p10.x,p10.y,p10.z,p10.w, p11.x,p11.y,p11.z,p11.w,
                                   p12.x,p12.y,p12.z,p12.w, p13.x,p13.y,p13.z,p13.w};
            const float q2v[16] = {p20.x,p20.y,p20.z,p20.w, p21.x,p21.y,p21.z,p21.w,
                                   p22.x,p22.y,p22.z,p22.w, p23.x,p23.y,p23.z,p23.w};
            #pragma unroll
            for (int j = 0; j < 16; ++j) {
                double u1 = (double)xs[j] - (double)q1v[j];
                double u2 = (double)xs[j] - (double)q2v[j];
                dd1 = fma(u1, u1, dd1);
                dd2 = fma(u2, u2, dd2);
            }
        }
        dd1 += __shfl_xor(dd1, 16, 64);  dd1 += __shfl_xor(dd1, 32, 64);
        dd2 += __shfl_xor(dd2, 16, 64);  dd2 += __shfl_xor(dd2, 32, 64);
        const bool take1 = (dd1 < dd2) || ((dd1 == dd2) && (i1 < i2));

        float4 q0, q1o, q2o, q3o;
        q0.x  = take1 ? p10.x : p20.x; q0.y  = take1 ? p10.y : p20.y;
        q0.z  = take1 ? p10.z : p20.z; q0.w  = take1 ? p10.w : p20.w;
        q1o.x = take1 ? p11.x : p21.x; q1o.y = take1 ? p11.y : p21.y;
        q1o.z = take1 ? p11.z : p21.z; q1o.w = take1 ? p11.w : p21.w;
        q2o.x = take1 ? p12.x : p22.x; q2o.y = take1 ? p12.y : p22.y;
        q2o.z = take1 ? p12.z : p22.z; q2o.w = take1 ? p12.w : p22.w;
        q3o.x = take1 ? p13.x : p23.x; q3o.y = take1 ? p13.y : p23.y;
        q3o.z = take1 ? p13.z : p23.z; q3o.w = take1 ? p13.w : p23.w;

        float* orow = out + (size_t)(rowbase + s * 16 + m) * VQ_D;
        *(float4*)(orow + 8 * g)          = q0;
        *(float4*)(orow + 8 * g + 4)      = q1o;
        *(float4*)(orow + 32 + 8 * g)     = q2o;
        *(float4*)(orow + 32 + 8 * g + 4) = q3o;

        float d;
        d = q0.x  - xa0[s].x; ls = fmaf(d, d, ls);  d = q0.y  - xa0[s].y; ls = fmaf(d, d, ls);
        d = q0.z  - xa0[s].z; ls = fmaf(d, d, ls);  d = q0.w  - xa0[s].w; ls = fmaf(d, d, ls);
        d = q1o.x - xa1[s].x; ls = fmaf(d, d, ls);  d = q1o.y - xa1[s].y; ls = fmaf(d, d, ls);
        d = q1o.z - xa1[s].z; ls = fmaf(d, d, ls);  d = q1o.w - xa1[s].w; ls = fmaf(d, d, ls);
        d = q2o.x - xb0[s].x; ls = fmaf(d, d, ls);  d = q2o.y - xb0[s].y; ls = fmaf(d, d, ls);
        d = q2o.z - xb0[s].z; ls = fmaf(d, d, ls);  d = q2o.w - xb0[s].w; ls = fmaf(d, d, ls);
        d = q3o.x - xb1[s].x; ls = fmaf(d, d, ls);  d = q3o.y - xb1[s].y; ls = fmaf(d, d, ls);
        d = q3o.z - xb1[s].z; ls = fmaf(d, d, ls);  d = q3o.w - xb1[s].w; ls = fmaf(d, d, ls);
    }

    #pragma unroll
    for (int off = 32; off > 0; off >>= 1) ls += __shfl_xor(ls, off, 64);

    __shared__ float lsw[16];
    if ((tid & 63) == 0) lsw[wid] = ls;
    __syncthreads();
    if (tid == 0) {
        float t = 0.f;
        #pragma unroll
        for (int wv = 0; wv < 16; ++wv) t += lsw[wv];
        partials[blockIdx.x] = t;
    }
}

// ---------------- finalize: deterministic partial-sum + scale ---------------------
__global__ __launch_bounds__(256) void vq_fin(const float* __restrict__ partials,
                                              float* __restrict__ out) {
    const int tid = threadIdx.x;
    float s = 0.f;
    #pragma unroll
    for (int j = 0; j < NBLK / 256; ++j) s += partials[tid + 256 * j];
    #pragma unroll
    for (int off = 32; off > 0; off >>= 1) s += __shfl_xor(s, off, 64);
    __shared__ float w[4];
    if ((tid & 63) == 0) w[tid >> 6] = s;
    __syncthreads();
    if (tid == 0)
        out[(size_t)VQ_N * VQ_D] = 1.25f * (w[0] + w[1] + w[2] + w[3]) / 8388608.0f;
}

extern "C" void kernel_launch(void* const* d_in, const int* in_sizes, int n_in,
                              void* d_out, int out_size, void* d_ws, size_t ws_size,
                              hipStream_t stream) {
    const float* x   = (const float*)d_in[0];   // (32,64,64,64) fp32
    const float* enc = (const float*)d_in[1];   // (64,512) fp32
    float* out = (float*)d_out;                 // 8388608 quantised + 1 loss
    float* ws  = (float*)d_ws;

    vq_prep<<<8, 64, 0, stream>>>(enc, ws);
    vq_main<<<NBLK, 1024, 0, stream>>>(x, ws, out, ws + WS_PART);
    vq_fin<<<1, 256, 0, stream>>>(ws + WS_PART, out);
}